// Round 1
// baseline (1251.962 us; speedup 1.0000x reference)
//
#include <hip/hip_runtime.h>
#include <hip/hip_bf16.h>

#define N_NODES 100000
#define N_EDGES 3200000
// F_IN=128, HID=64, C=16

__device__ __forceinline__ float f4c(const float4& v, int k) {
    switch (k & 3) { case 0: return v.x; case 1: return v.y; case 2: return v.z; default: return v.w; }
}
__device__ __forceinline__ void fma4(float4& a, float s, const float4& w) {
    a.x += s * w.x; a.y += s * w.y; a.z += s * w.z; a.w += s * w.w;
}

// ---------------- CSR build ----------------

__global__ __launch_bounds__(256) void zero_kernel(int* __restrict__ p, int n) {
    int i = blockIdx.x * 256 + threadIdx.x;
    if (i < n) p[i] = 0;
}

__global__ __launch_bounds__(256) void hist_kernel(const int* __restrict__ dst, int* __restrict__ hist) {
    int e = blockIdx.x * 256 + threadIdx.x;
    if (e < N_EDGES) atomicAdd(&hist[dst[e]], 1);
}

// single block, 1024 threads: exclusive scan of hist -> row_start[N+1], cursor copy, dis = rsqrt(deg+1)
__global__ __launch_bounds__(1024) void scan_kernel(const int* __restrict__ hist,
                                                    int* __restrict__ row_start,
                                                    int* __restrict__ cursor,
                                                    float* __restrict__ dis) {
    __shared__ int wsum[16];
    const int tid = threadIdx.x;
    const int lane = tid & 63;
    const int wid = tid >> 6;
    int carry = 0;
    const int CHUNK = 8192;  // 1024 threads * 8 elems
    for (int base = 0; base < N_NODES; base += CHUNK) {
        int idx0 = base + tid * 8;
        int v[8];
#pragma unroll
        for (int i = 0; i < 8; ++i) {
            int idx = idx0 + i;
            v[i] = (idx < N_NODES) ? hist[idx] : 0;
        }
        int tsum = 0;
#pragma unroll
        for (int i = 0; i < 8; ++i) tsum += v[i];
        // wave inclusive scan of per-thread sums
        int incl = tsum;
#pragma unroll
        for (int off = 1; off < 64; off <<= 1) {
            int t = __shfl_up(incl, (unsigned)off, 64);
            if (lane >= off) incl += t;
        }
        if (lane == 63) wsum[wid] = incl;
        __syncthreads();
        int wprefix = 0, ctotal = 0;
#pragma unroll
        for (int w = 0; w < 16; ++w) {
            int sv = wsum[w];
            if (w < wid) wprefix += sv;
            ctotal += sv;
        }
        int run = carry + wprefix + (incl - tsum);
#pragma unroll
        for (int i = 0; i < 8; ++i) {
            int idx = idx0 + i;
            if (idx < N_NODES) {
                row_start[idx] = run;
                cursor[idx] = run;
                dis[idx] = rsqrtf((float)v[i] + 1.0f);
                run += v[i];
            }
        }
        carry += ctotal;
        __syncthreads();
    }
    if (tid == 0) row_start[N_NODES] = carry;
}

__global__ __launch_bounds__(256) void fill_kernel(const int* __restrict__ src, const int* __restrict__ dst,
                                                   int* __restrict__ cursor, int* __restrict__ s_src) {
    int e = blockIdx.x * 256 + threadIdx.x;
    if (e < N_EDGES) {
        int d = dst[e];
        int pos = atomicAdd(&cursor[d], 1);
        s_src[pos] = src[e];
    }
}

// ---------------- dense lin: Y[N,O] = X[N,K] @ W[K,O] ----------------

template <int K, int O>
__global__ __launch_bounds__(256) void lin_kernel(const float* __restrict__ X, const float* __restrict__ W,
                                                  float* __restrict__ Y) {
    __shared__ float4 Wl[K * O / 4];
    const int tid = threadIdx.x;
    for (int i = tid; i < K * O / 4; i += 256) Wl[i] = reinterpret_cast<const float4*>(W)[i];
    __syncthreads();
    const int node = blockIdx.x * 256 + tid;
    if (node >= N_NODES) return;
    float4 acc[O / 4];
#pragma unroll
    for (int j = 0; j < O / 4; ++j) acc[j] = make_float4(0.f, 0.f, 0.f, 0.f);
    const float4* Xr = reinterpret_cast<const float4*>(X + (size_t)node * K);
#pragma unroll 2
    for (int k4 = 0; k4 < K / 4; ++k4) {
        float4 xv = Xr[k4];
#pragma unroll
        for (int kk = 0; kk < 4; ++kk) {
            float xs = f4c(xv, kk);
#pragma unroll
            for (int j = 0; j < O / 4; ++j) fma4(acc[j], xs, Wl[(k4 * 4 + kk) * (O / 4) + j]);
        }
    }
    float4* Yr = reinterpret_cast<float4*>(Y + (size_t)node * O);
#pragma unroll
    for (int j = 0; j < O / 4; ++j) Yr[j] = acc[j];
}

// ---------------- aggregation (gather over CSR) ----------------
// Y[i,:] = maybe_relu( sum_{e in row(i)} H[s_e,:]*dis[s_e]*dis[i] + H[i,:]*dis[i]^2 + bias ) (+ Y[i,:] if RESIDUAL)

template <bool RELU, bool RESIDUAL>
__global__ __launch_bounds__(256) void agg64_kernel(const float* __restrict__ H, float* __restrict__ Y,
                                                    const float* __restrict__ dis,
                                                    const int* __restrict__ row_start,
                                                    const int* __restrict__ s_src,
                                                    const float* __restrict__ bias) {
    const int tid = threadIdx.x;
    const int lane = tid & 63;
    const int wid = tid >> 6;
    const int node = blockIdx.x * 4 + wid;
    if (node >= N_NODES) return;
    const float di = dis[node];
    const int j = lane;
    float acc = H[(size_t)node * 64 + j] * di * di + bias[j];
    const int rs = row_start[node], re = row_start[node + 1];
    int e = rs;
    for (; e + 2 <= re; e += 2) {
        int s0 = s_src[e], s1 = s_src[e + 1];
        float n0 = dis[s0] * di, n1 = dis[s1] * di;
        acc += H[(size_t)s0 * 64 + j] * n0;
        acc += H[(size_t)s1 * 64 + j] * n1;
    }
    if (e < re) {
        int s0 = s_src[e];
        acc += H[(size_t)s0 * 64 + j] * (dis[s0] * di);
    }
    if (RELU) acc = fmaxf(acc, 0.0f);
    float out = acc;
    if (RESIDUAL) out += Y[(size_t)node * 64 + j];
    Y[(size_t)node * 64 + j] = out;
}

__global__ __launch_bounds__(256) void agg16_kernel(const float* __restrict__ H, float* __restrict__ Y,
                                                    const float* __restrict__ dis,
                                                    const int* __restrict__ row_start,
                                                    const int* __restrict__ s_src,
                                                    const float* __restrict__ bias) {
    const int tid = threadIdx.x;
    const int j = tid & 15;
    const int node = blockIdx.x * 16 + (tid >> 4);
    if (node >= N_NODES) return;
    const float di = dis[node];
    float acc = H[(size_t)node * 16 + j] * di * di + bias[j];
    const int rs = row_start[node], re = row_start[node + 1];
    for (int e = rs; e < re; ++e) {
        int s = s_src[e];
        acc += H[(size_t)s * 16 + j] * (dis[s] * di);
    }
    Y[(size_t)node * 16 + j] = acc;
}

// ---------------- edge MLP + log_softmax ----------------

__global__ __launch_bounds__(256) void edge_mlp_kernel(const float* __restrict__ H3,
                                                       const int* __restrict__ src, const int* __restrict__ dst,
                                                       const float* __restrict__ fc1W, const float* __restrict__ fc1b,
                                                       const float* __restrict__ fc2W, const float* __restrict__ fc2b,
                                                       float* __restrict__ out) {
    __shared__ float4 sW1[32 * 4];   // fc1_W [32][16]
    __shared__ float4 sW2[16 * 4];   // fc2_W [16][16]
    __shared__ float4 sB1[4];
    __shared__ float4 sB2[4];
    const int tid = threadIdx.x;
    if (tid < 128) sW1[tid] = reinterpret_cast<const float4*>(fc1W)[tid];
    else if (tid < 192) sW2[tid - 128] = reinterpret_cast<const float4*>(fc2W)[tid - 128];
    else if (tid < 196) sB1[tid - 192] = reinterpret_cast<const float4*>(fc1b)[tid - 192];
    else if (tid < 200) sB2[tid - 196] = reinterpret_cast<const float4*>(fc2b)[tid - 196];
    __syncthreads();
    const int e = blockIdx.x * 256 + tid;
    if (e >= N_EDGES) return;
    const int s = src[e], d = dst[e];
    const float4* Hs = reinterpret_cast<const float4*>(H3) + (size_t)s * 4;
    const float4* Hd = reinterpret_cast<const float4*>(H3) + (size_t)d * 4;
    float4 hs[4], hd[4];
#pragma unroll
    for (int q = 0; q < 4; ++q) { hs[q] = Hs[q]; hd[q] = Hd[q]; }
    float4 t[4];
#pragma unroll
    for (int q = 0; q < 4; ++q) t[q] = sB1[q];
#pragma unroll
    for (int k = 0; k < 16; ++k) {
        float a = f4c(hs[k >> 2], k & 3);
#pragma unroll
        for (int q = 0; q < 4; ++q) fma4(t[q], a, sW1[k * 4 + q]);
    }
#pragma unroll
    for (int k = 0; k < 16; ++k) {
        float a = f4c(hd[k >> 2], k & 3);
#pragma unroll
        for (int q = 0; q < 4; ++q) fma4(t[q], a, sW1[(16 + k) * 4 + q]);
    }
#pragma unroll
    for (int q = 0; q < 4; ++q) {
        t[q].x = fmaxf(t[q].x, 0.f); t[q].y = fmaxf(t[q].y, 0.f);
        t[q].z = fmaxf(t[q].z, 0.f); t[q].w = fmaxf(t[q].w, 0.f);
    }
    float4 o[4];
#pragma unroll
    for (int q = 0; q < 4; ++q) o[q] = sB2[q];
#pragma unroll
    for (int k = 0; k < 16; ++k) {
        float a = f4c(t[k >> 2], k & 3);
#pragma unroll
        for (int q = 0; q < 4; ++q) fma4(o[q], a, sW2[k * 4 + q]);
    }
    // log_softmax over the 16 outputs
    float m = o[0].x;
#pragma unroll
    for (int q = 0; q < 4; ++q) {
        m = fmaxf(m, o[q].x); m = fmaxf(m, o[q].y);
        m = fmaxf(m, o[q].z); m = fmaxf(m, o[q].w);
    }
    float sum = 0.f;
#pragma unroll
    for (int q = 0; q < 4; ++q) {
        sum += __expf(o[q].x - m); sum += __expf(o[q].y - m);
        sum += __expf(o[q].z - m); sum += __expf(o[q].w - m);
    }
    float ls = m + __logf(sum);
    float4* Or = reinterpret_cast<float4*>(out) + (size_t)e * 4;
#pragma unroll
    for (int q = 0; q < 4; ++q) {
        float4 r;
        r.x = o[q].x - ls; r.y = o[q].y - ls; r.z = o[q].z - ls; r.w = o[q].w - ls;
        Or[q] = r;
    }
}

// ---------------- launch ----------------

extern "C" void kernel_launch(void* const* d_in, const int* in_sizes, int n_in,
                              void* d_out, int out_size, void* d_ws, size_t ws_size,
                              hipStream_t stream) {
    (void)in_sizes; (void)n_in; (void)out_size; (void)ws_size;
    const float* x    = (const float*)d_in[0];
    const int* eidx   = (const int*)d_in[1];
    const float* W1   = (const float*)d_in[2];
    const float* b1   = (const float*)d_in[3];
    const float* W2   = (const float*)d_in[4];
    const float* b2   = (const float*)d_in[5];
    const float* W3   = (const float*)d_in[6];
    const float* b3   = (const float*)d_in[7];
    const float* fc1W = (const float*)d_in[8];
    const float* fc1b = (const float*)d_in[9];
    const float* fc2W = (const float*)d_in[10];
    const float* fc2b = (const float*)d_in[11];
    const int* src = eidx;
    const int* dst = eidx + N_EDGES;

    char* ws = (char*)d_ws;
    size_t off = 0;
    auto alloc = [&](size_t bytes) { size_t cur = off; off = (cur + bytes + 255) & ~(size_t)255; return cur; };
    int*   hist      = (int*)(ws + alloc((size_t)N_NODES * 4));
    int*   row_start = (int*)(ws + alloc((size_t)(N_NODES + 1) * 4));
    int*   cursor    = (int*)(ws + alloc((size_t)N_NODES * 4));
    float* dis       = (float*)(ws + alloc((size_t)N_NODES * 4));
    int*   s_src     = (int*)(ws + alloc((size_t)N_EDGES * 4));
    float* A         = (float*)(ws + alloc((size_t)N_NODES * 64 * 4));
    float* B         = (float*)(ws + alloc((size_t)N_NODES * 64 * 4));
    float* outp      = (float*)d_out;

    const int nblkN = (N_NODES + 255) / 256;
    const int nblkE = (N_EDGES + 255) / 256;

    // CSR build + degrees
    zero_kernel<<<nblkN, 256, 0, stream>>>(hist, N_NODES);
    hist_kernel<<<nblkE, 256, 0, stream>>>(dst, hist);
    scan_kernel<<<1, 1024, 0, stream>>>(hist, row_start, cursor, dis);
    fill_kernel<<<nblkE, 256, 0, stream>>>(src, dst, cursor, s_src);

    // conv1: A = x@W1 ; B = relu(agg(A)+b1)          (h1)
    lin_kernel<128, 64><<<nblkN, 256, 0, stream>>>(x, W1, A);
    agg64_kernel<true, false><<<(N_NODES + 3) / 4, 256, 0, stream>>>(A, B, dis, row_start, s_src, b1);
    // conv2: A = B@W2 ; B = relu(agg(A)+b2) + B      (h2, in-place residual)
    lin_kernel<64, 64><<<nblkN, 256, 0, stream>>>(B, W2, A);
    agg64_kernel<true, true><<<(N_NODES + 3) / 4, 256, 0, stream>>>(A, B, dis, row_start, s_src, b2);
    // conv3: A16 = B@W3 ; B16 = agg(A16)+b3          (h3)
    lin_kernel<64, 16><<<nblkN, 256, 0, stream>>>(B, W3, A);
    agg16_kernel<<<(N_NODES + 15) / 16, 256, 0, stream>>>(A, B, dis, row_start, s_src, b3);
    // edge MLP + log_softmax
    edge_mlp_kernel<<<nblkE, 256, 0, stream>>>(B, src, dst, fc1W, fc1b, fc2W, fc2b, outp);
}

// Round 2
// 750.428 us; speedup vs baseline: 1.6683x; 1.6683x over previous
//
#include <hip/hip_runtime.h>
#include <hip/hip_bf16.h>

#define N_NODES 100000
#define N_EDGES 3200000
#define NBUCK 782          // ceil(100000/128) buckets of 128 nodes
#define P1_CHUNK 6144      // edges per p1b block
#define BCAP 4800          // max edges per bucket (mean 4092, sd ~64 -> 11 sigma margin)

__device__ __forceinline__ float f4c(const float4& v, int k) {
    switch (k & 3) { case 0: return v.x; case 1: return v.y; case 2: return v.z; default: return v.w; }
}
__device__ __forceinline__ void fma4(float4& a, float s, const float4& w) {
    a.x += s * w.x; a.y += s * w.y; a.z += s * w.z; a.w += s * w.w;
}

// ---------------- CSR build (2-level counting sort, coalesced writes) ----------------

__global__ __launch_bounds__(256) void zero_kernel(int* __restrict__ p, int n) {
    int i = blockIdx.x * 256 + threadIdx.x;
    if (i < n) p[i] = 0;
}

// bucket histogram, LDS-aggregated
__global__ __launch_bounds__(256) void p1a_hist(const int* __restrict__ dst, int* __restrict__ bhist) {
    __shared__ int lhist[NBUCK];
    const int tid = threadIdx.x;
    for (int i = tid; i < NBUCK; i += 256) lhist[i] = 0;
    __syncthreads();
    const long e0 = (long)blockIdx.x * 8192;
    for (int i = tid; i < 8192; i += 256) {
        long e = e0 + i;
        if (e < N_EDGES) atomicAdd(&lhist[dst[e] >> 7], 1);
    }
    __syncthreads();
    for (int i = tid; i < NBUCK; i += 256) {
        int c = lhist[i];
        if (c > 0) atomicAdd(&bhist[i], c);
    }
}

// single block: exclusive scan of 782 bucket counts -> bucket_start[783], cursor copy
__global__ __launch_bounds__(256) void scan_buckets(const int* __restrict__ bhist,
                                                    int* __restrict__ bucket_start,
                                                    int* __restrict__ bucket_cursor) {
    __shared__ int wpart[4];
    const int tid = threadIdx.x;
    const int lane = tid & 63;
    const int wid = tid >> 6;
    int c[4];
    const int idx0 = tid * 4;
    int tsum = 0;
#pragma unroll
    for (int i = 0; i < 4; ++i) {
        int id = idx0 + i;
        c[i] = (id < NBUCK) ? bhist[id] : 0;
        tsum += c[i];
    }
    int incl = tsum;
#pragma unroll
    for (int off = 1; off < 64; off <<= 1) {
        int t = __shfl_up(incl, (unsigned)off, 64);
        if (lane >= off) incl += t;
    }
    if (lane == 63) wpart[wid] = incl;
    __syncthreads();
    int wpre = 0, total = 0;
#pragma unroll
    for (int w = 0; w < 4; ++w) { int sv = wpart[w]; if (w < wid) wpre += sv; total += sv; }
    int run = wpre + incl - tsum;
#pragma unroll
    for (int i = 0; i < 4; ++i) {
        int id = idx0 + i;
        if (id < NBUCK) { bucket_start[id] = run; bucket_cursor[id] = run; run += c[i]; }
    }
    if (tid == 0) bucket_start[NBUCK] = total;
}

// scatter (src,dst) pairs into bucket regions of tmp, LDS-staged for coalesced writes
__global__ __launch_bounds__(256) void p1b_scatter(const int* __restrict__ src, const int* __restrict__ dst,
                                                   int* __restrict__ bucket_cursor, uint2* __restrict__ tmp) {
    __shared__ uint2 stage[P1_CHUNK];   // 48 KB
    __shared__ int lhist[NBUCK];
    __shared__ int lbase[NBUCK];
    __shared__ int gbase[NBUCK];
    __shared__ int wpart[4];
    const int tid = threadIdx.x;
    const int lane = tid & 63;
    const int wid = tid >> 6;
    const long e0 = (long)blockIdx.x * P1_CHUNK;
    const int nvalid = (int)min((long)P1_CHUNK, (long)N_EDGES - e0);
    for (int i = tid; i < NBUCK; i += 256) lhist[i] = 0;
    __syncthreads();
    // pass A: local bucket counts
    for (int i = tid; i < nvalid; i += 256) {
        atomicAdd(&lhist[dst[e0 + i] >> 7], 1);
    }
    __syncthreads();
    // exclusive scan lhist -> lbase
    int c[4];
    const int idx0 = tid * 4;
    int tsum = 0;
#pragma unroll
    for (int i = 0; i < 4; ++i) {
        int id = idx0 + i;
        c[i] = (id < NBUCK) ? lhist[id] : 0;
        tsum += c[i];
    }
    int incl = tsum;
#pragma unroll
    for (int off = 1; off < 64; off <<= 1) {
        int t = __shfl_up(incl, (unsigned)off, 64);
        if (lane >= off) incl += t;
    }
    if (lane == 63) wpart[wid] = incl;
    __syncthreads();
    int wpre = 0;
#pragma unroll
    for (int w = 0; w < 4; ++w) { if (w < wid) wpre += wpart[w]; }
    int run = wpre + incl - tsum;
#pragma unroll
    for (int i = 0; i < 4; ++i) {
        int id = idx0 + i;
        if (id < NBUCK) { lbase[id] = run; run += c[i]; }
    }
    __syncthreads();
    // reserve global ranges (one atomic per nonempty bucket per block)
    for (int i = tid; i < NBUCK; i += 256) {
        int cnt = lhist[i];
        gbase[i] = (cnt > 0) ? atomicAdd(&bucket_cursor[i], cnt) : 0;
    }
    __syncthreads();
    // zero lhist -> reuse as pass-B cursors
    for (int i = tid; i < NBUCK; i += 256) lhist[i] = 0;
    __syncthreads();
    // pass B: stage pairs grouped by bucket
    for (int i = tid; i < nvalid; i += 256) {
        int d = dst[e0 + i];
        int s = src[e0 + i];
        int b = d >> 7;
        int r = atomicAdd(&lhist[b], 1);
        stage[lbase[b] + r] = make_uint2((unsigned)s, (unsigned)d);
    }
    __syncthreads();
    // coalesced copy-out (bucket-contiguous runs)
    for (int i = tid; i < nvalid; i += 256) {
        uint2 p = stage[i];
        int b = (int)(p.y >> 7);
        long gp = (long)gbase[b] + (i - lbase[b]);
        tmp[gp] = p;
    }
}

// per-bucket counting sort in LDS -> s_src coalesced; also emits row_start and dis
__global__ __launch_bounds__(256) void p2_sort(const uint2* __restrict__ tmp, const int* __restrict__ bucket_start,
                                               int* __restrict__ s_src, int* __restrict__ row_start,
                                               float* __restrict__ dis) {
    __shared__ int src_l[BCAP];                 // 19.2 KB
    __shared__ unsigned short lid_l[BCAP];      // 9.6 KB
    __shared__ int sorted[BCAP];                // 19.2 KB
    __shared__ int cnt128[128];
    __shared__ int pref[129];
    __shared__ int w2[2];
    const int b = blockIdx.x;
    const int tid = threadIdx.x;
    const int lane = tid & 63;
    const int base = bucket_start[b];
    const int end = bucket_start[b + 1];
    int cnt = end - base;
    if (cnt > BCAP) cnt = BCAP;   // safety clamp (never hit for this data)
    const int nbase = b << 7;
    for (int i = tid; i < 128; i += 256) cnt128[i] = 0;
    __syncthreads();
    for (int i = tid; i < cnt; i += 256) {
        uint2 p = tmp[base + i];
        src_l[i] = (int)p.x;
        int l = (int)p.y - nbase;
        lid_l[i] = (unsigned short)l;
        atomicAdd(&cnt128[l], 1);
    }
    __syncthreads();
    // exclusive scan of cnt128 -> pref
    int v = (tid < 128) ? cnt128[tid] : 0;
    int incl = v;
#pragma unroll
    for (int off = 1; off < 64; off <<= 1) {
        int t = __shfl_up(incl, (unsigned)off, 64);
        if (lane >= off) incl += t;
    }
    if (tid < 128 && lane == 63) w2[tid >> 6] = incl;
    __syncthreads();
    if (tid < 128 && (tid >> 6) == 1) incl += w2[0];
    if (tid < 128) { pref[tid + 1] = incl; if (tid == 0) pref[0] = 0; }
    __syncthreads();
    // row_start + dis for this bucket's nodes
    const int nnodes = min(128, N_NODES - nbase);
    if (tid < nnodes) {
        row_start[nbase + tid] = base + pref[tid];
        dis[nbase + tid] = rsqrtf((float)cnt128[tid] + 1.0f);
    }
    if (b == NBUCK - 1 && tid == 0) row_start[N_NODES] = base + cnt;
    // reuse cnt128 as scatter cursors
    if (tid < 128) cnt128[tid] = pref[tid];
    __syncthreads();
    for (int i = tid; i < cnt; i += 256) {
        int l = lid_l[i];
        int pos = atomicAdd(&cnt128[l], 1);
        sorted[pos] = src_l[i];
    }
    __syncthreads();
    for (int i = tid; i < cnt; i += 256) s_src[base + i] = sorted[i];
}

// ---------------- dense lin: Y[N,O] = X[N,K] @ W[K,O] ----------------

template <int K, int O>
__global__ __launch_bounds__(256) void lin_kernel(const float* __restrict__ X, const float* __restrict__ W,
                                                  float* __restrict__ Y) {
    __shared__ float4 Wl[K * O / 4];
    const int tid = threadIdx.x;
    for (int i = tid; i < K * O / 4; i += 256) Wl[i] = reinterpret_cast<const float4*>(W)[i];
    __syncthreads();
    const int node = blockIdx.x * 256 + tid;
    if (node >= N_NODES) return;
    float4 acc[O / 4];
#pragma unroll
    for (int j = 0; j < O / 4; ++j) acc[j] = make_float4(0.f, 0.f, 0.f, 0.f);
    const float4* Xr = reinterpret_cast<const float4*>(X + (size_t)node * K);
#pragma unroll 2
    for (int k4 = 0; k4 < K / 4; ++k4) {
        float4 xv = Xr[k4];
#pragma unroll
        for (int kk = 0; kk < 4; ++kk) {
            float xs = f4c(xv, kk);
#pragma unroll
            for (int j = 0; j < O / 4; ++j) fma4(acc[j], xs, Wl[(k4 * 4 + kk) * (O / 4) + j]);
        }
    }
    float4* Yr = reinterpret_cast<float4*>(Y + (size_t)node * O);
#pragma unroll
    for (int j = 0; j < O / 4; ++j) Yr[j] = acc[j];
}

// ---------------- aggregation (gather over CSR) ----------------

template <bool RELU, bool RESIDUAL>
__global__ __launch_bounds__(256) void agg64_kernel(const float* __restrict__ H, float* __restrict__ Y,
                                                    const float* __restrict__ dis,
                                                    const int* __restrict__ row_start,
                                                    const int* __restrict__ s_src,
                                                    const float* __restrict__ bias) {
    const int tid = threadIdx.x;
    const int lane = tid & 63;
    const int wid = tid >> 6;
    const int node = blockIdx.x * 4 + wid;
    if (node >= N_NODES) return;
    const float di = dis[node];
    const int j = lane;
    float acc = H[(size_t)node * 64 + j] * di * di + bias[j];
    const int rs = row_start[node], re = row_start[node + 1];
    int e = rs;
    for (; e + 2 <= re; e += 2) {
        int s0 = s_src[e], s1 = s_src[e + 1];
        float n0 = dis[s0] * di, n1 = dis[s1] * di;
        acc += H[(size_t)s0 * 64 + j] * n0;
        acc += H[(size_t)s1 * 64 + j] * n1;
    }
    if (e < re) {
        int s0 = s_src[e];
        acc += H[(size_t)s0 * 64 + j] * (dis[s0] * di);
    }
    if (RELU) acc = fmaxf(acc, 0.0f);
    float out = acc;
    if (RESIDUAL) out += Y[(size_t)node * 64 + j];
    Y[(size_t)node * 64 + j] = out;
}

__global__ __launch_bounds__(256) void agg16_kernel(const float* __restrict__ H, float* __restrict__ Y,
                                                    const float* __restrict__ dis,
                                                    const int* __restrict__ row_start,
                                                    const int* __restrict__ s_src,
                                                    const float* __restrict__ bias) {
    const int tid = threadIdx.x;
    const int j = tid & 15;
    const int node = blockIdx.x * 16 + (tid >> 4);
    if (node >= N_NODES) return;
    const float di = dis[node];
    float acc = H[(size_t)node * 16 + j] * di * di + bias[j];
    const int rs = row_start[node], re = row_start[node + 1];
    for (int e = rs; e < re; ++e) {
        int s = s_src[e];
        acc += H[(size_t)s * 16 + j] * (dis[s] * di);
    }
    Y[(size_t)node * 16 + j] = acc;
}

// ---------------- edge MLP + log_softmax ----------------

__global__ __launch_bounds__(256) void edge_mlp_kernel(const float* __restrict__ H3,
                                                       const int* __restrict__ src, const int* __restrict__ dst,
                                                       const float* __restrict__ fc1W, const float* __restrict__ fc1b,
                                                       const float* __restrict__ fc2W, const float* __restrict__ fc2b,
                                                       float* __restrict__ out) {
    __shared__ float4 sW1[32 * 4];   // fc1_W [32][16]
    __shared__ float4 sW2[16 * 4];   // fc2_W [16][16]
    __shared__ float4 sB1[4];
    __shared__ float4 sB2[4];
    const int tid = threadIdx.x;
    if (tid < 128) sW1[tid] = reinterpret_cast<const float4*>(fc1W)[tid];
    else if (tid < 192) sW2[tid - 128] = reinterpret_cast<const float4*>(fc2W)[tid - 128];
    else if (tid < 196) sB1[tid - 192] = reinterpret_cast<const float4*>(fc1b)[tid - 192];
    else if (tid < 200) sB2[tid - 196] = reinterpret_cast<const float4*>(fc2b)[tid - 196];
    __syncthreads();
    const int e = blockIdx.x * 256 + tid;
    if (e >= N_EDGES) return;
    const int s = src[e], d = dst[e];
    const float4* Hs = reinterpret_cast<const float4*>(H3) + (size_t)s * 4;
    const float4* Hd = reinterpret_cast<const float4*>(H3) + (size_t)d * 4;
    float4 hs[4], hd[4];
#pragma unroll
    for (int q = 0; q < 4; ++q) { hs[q] = Hs[q]; hd[q] = Hd[q]; }
    float4 t[4];
#pragma unroll
    for (int q = 0; q < 4; ++q) t[q] = sB1[q];
#pragma unroll
    for (int k = 0; k < 16; ++k) {
        float a = f4c(hs[k >> 2], k & 3);
#pragma unroll
        for (int q = 0; q < 4; ++q) fma4(t[q], a, sW1[k * 4 + q]);
    }
#pragma unroll
    for (int k = 0; k < 16; ++k) {
        float a = f4c(hd[k >> 2], k & 3);
#pragma unroll
        for (int q = 0; q < 4; ++q) fma4(t[q], a, sW1[(16 + k) * 4 + q]);
    }
#pragma unroll
    for (int q = 0; q < 4; ++q) {
        t[q].x = fmaxf(t[q].x, 0.f); t[q].y = fmaxf(t[q].y, 0.f);
        t[q].z = fmaxf(t[q].z, 0.f); t[q].w = fmaxf(t[q].w, 0.f);
    }
    float4 o[4];
#pragma unroll
    for (int q = 0; q < 4; ++q) o[q] = sB2[q];
#pragma unroll
    for (int k = 0; k < 16; ++k) {
        float a = f4c(t[k >> 2], k & 3);
#pragma unroll
        for (int q = 0; q < 4; ++q) fma4(o[q], a, sW2[k * 4 + q]);
    }
    float m = o[0].x;
#pragma unroll
    for (int q = 0; q < 4; ++q) {
        m = fmaxf(m, o[q].x); m = fmaxf(m, o[q].y);
        m = fmaxf(m, o[q].z); m = fmaxf(m, o[q].w);
    }
    float sum = 0.f;
#pragma unroll
    for (int q = 0; q < 4; ++q) {
        sum += __expf(o[q].x - m); sum += __expf(o[q].y - m);
        sum += __expf(o[q].z - m); sum += __expf(o[q].w - m);
    }
    float ls = m + __logf(sum);
    float4* Or = reinterpret_cast<float4*>(out) + (size_t)e * 4;
#pragma unroll
    for (int q = 0; q < 4; ++q) {
        float4 r;
        r.x = o[q].x - ls; r.y = o[q].y - ls; r.z = o[q].z - ls; r.w = o[q].w - ls;
        Or[q] = r;
    }
}

// ---------------- launch ----------------

extern "C" void kernel_launch(void* const* d_in, const int* in_sizes, int n_in,
                              void* d_out, int out_size, void* d_ws, size_t ws_size,
                              hipStream_t stream) {
    (void)in_sizes; (void)n_in; (void)out_size; (void)ws_size;
    const float* x    = (const float*)d_in[0];
    const int* eidx   = (const int*)d_in[1];
    const float* W1   = (const float*)d_in[2];
    const float* b1   = (const float*)d_in[3];
    const float* W2   = (const float*)d_in[4];
    const float* b2   = (const float*)d_in[5];
    const float* W3   = (const float*)d_in[6];
    const float* b3   = (const float*)d_in[7];
    const float* fc1W = (const float*)d_in[8];
    const float* fc1b = (const float*)d_in[9];
    const float* fc2W = (const float*)d_in[10];
    const float* fc2b = (const float*)d_in[11];
    const int* src = eidx;
    const int* dst = eidx + N_EDGES;

    char* ws = (char*)d_ws;
    size_t off = 0;
    auto alloc = [&](size_t bytes) { size_t cur = off; off = (cur + bytes + 255) & ~(size_t)255; return cur; };
    int*   bhist         = (int*)(ws + alloc((size_t)NBUCK * 4));
    int*   bucket_start  = (int*)(ws + alloc((size_t)(NBUCK + 1) * 4));
    int*   bucket_cursor = (int*)(ws + alloc((size_t)NBUCK * 4));
    int*   row_start     = (int*)(ws + alloc((size_t)(N_NODES + 1) * 4));
    float* dis           = (float*)(ws + alloc((size_t)N_NODES * 4));
    int*   s_src         = (int*)(ws + alloc((size_t)N_EDGES * 4));
    float* A             = (float*)(ws + alloc((size_t)N_NODES * 64 * 4));
    float* B             = (float*)(ws + alloc((size_t)N_NODES * 64 * 4));
    uint2* tmp           = (uint2*)A;   // pairs buffer aliases A (consumed before lin1 writes A)
    float* outp          = (float*)d_out;

    const int nblkN = (N_NODES + 255) / 256;
    const int nblkE = (N_EDGES + 255) / 256;

    // CSR build
    zero_kernel<<<(NBUCK + 255) / 256, 256, 0, stream>>>(bhist, NBUCK);
    p1a_hist<<<(N_EDGES + 8191) / 8192, 256, 0, stream>>>(dst, bhist);
    scan_buckets<<<1, 256, 0, stream>>>(bhist, bucket_start, bucket_cursor);
    p1b_scatter<<<(N_EDGES + P1_CHUNK - 1) / P1_CHUNK, 256, 0, stream>>>(src, dst, bucket_cursor, tmp);
    p2_sort<<<NBUCK, 256, 0, stream>>>(tmp, bucket_start, s_src, row_start, dis);

    // conv1: A = x@W1 ; B = relu(agg(A)+b1)
    lin_kernel<128, 64><<<nblkN, 256, 0, stream>>>(x, W1, A);
    agg64_kernel<true, false><<<(N_NODES + 3) / 4, 256, 0, stream>>>(A, B, dis, row_start, s_src, b1);
    // conv2: A = B@W2 ; B = relu(agg(A)+b2) + B
    lin_kernel<64, 64><<<nblkN, 256, 0, stream>>>(B, W2, A);
    agg64_kernel<true, true><<<(N_NODES + 3) / 4, 256, 0, stream>>>(A, B, dis, row_start, s_src, b2);
    // conv3: A16 = B@W3 ; B16 = agg(A16)+b3
    lin_kernel<64, 16><<<nblkN, 256, 0, stream>>>(B, W3, A);
    agg16_kernel<<<(N_NODES + 15) / 16, 256, 0, stream>>>(A, B, dis, row_start, s_src, b3);
    // edge MLP + log_softmax
    edge_mlp_kernel<<<nblkE, 256, 0, stream>>>(B, src, dst, fc1W, fc1b, fc2W, fc2b, outp);
}

// Round 3
// 475.429 us; speedup vs baseline: 2.6333x; 1.5784x over previous
//
#include <hip/hip_runtime.h>
#include <hip/hip_bf16.h>
#include <hip/hip_fp16.h>

#define N_NODES 100000
#define N_EDGES 3200000
#define NBUCK 782          // ceil(100000/128) buckets of 128 nodes
#define P1_CHUNK 6144      // edges per p1b block
#define BCAP 4800          // max edges per bucket (mean 4092, sd ~64)

__device__ __forceinline__ float f4c(const float4& v, int k) {
    switch (k & 3) { case 0: return v.x; case 1: return v.y; case 2: return v.z; default: return v.w; }
}
__device__ __forceinline__ void fma4(float4& a, float s, const float4& w) {
    a.x += s * w.x; a.y += s * w.y; a.z += s * w.z; a.w += s * w.w;
}

// ---------------- CSR build (2-level counting sort, coalesced writes) ----------------

__global__ __launch_bounds__(256) void zero_kernel(int* __restrict__ p, int n) {
    int i = blockIdx.x * 256 + threadIdx.x;
    if (i < n) p[i] = 0;
}

__global__ __launch_bounds__(256) void p1a_hist(const int* __restrict__ dst, int* __restrict__ bhist) {
    __shared__ int lhist[NBUCK];
    const int tid = threadIdx.x;
    for (int i = tid; i < NBUCK; i += 256) lhist[i] = 0;
    __syncthreads();
    const long e0 = (long)blockIdx.x * 8192;
    for (int i = tid; i < 8192; i += 256) {
        long e = e0 + i;
        if (e < N_EDGES) atomicAdd(&lhist[dst[e] >> 7], 1);
    }
    __syncthreads();
    for (int i = tid; i < NBUCK; i += 256) {
        int c = lhist[i];
        if (c > 0) atomicAdd(&bhist[i], c);
    }
}

__global__ __launch_bounds__(256) void scan_buckets(const int* __restrict__ bhist,
                                                    int* __restrict__ bucket_start,
                                                    int* __restrict__ bucket_cursor) {
    __shared__ int wpart[4];
    const int tid = threadIdx.x;
    const int lane = tid & 63;
    const int wid = tid >> 6;
    int c[4];
    const int idx0 = tid * 4;
    int tsum = 0;
#pragma unroll
    for (int i = 0; i < 4; ++i) {
        int id = idx0 + i;
        c[i] = (id < NBUCK) ? bhist[id] : 0;
        tsum += c[i];
    }
    int incl = tsum;
#pragma unroll
    for (int off = 1; off < 64; off <<= 1) {
        int t = __shfl_up(incl, (unsigned)off, 64);
        if (lane >= off) incl += t;
    }
    if (lane == 63) wpart[wid] = incl;
    __syncthreads();
    int wpre = 0, total = 0;
#pragma unroll
    for (int w = 0; w < 4; ++w) { int sv = wpart[w]; if (w < wid) wpre += sv; total += sv; }
    int run = wpre + incl - tsum;
#pragma unroll
    for (int i = 0; i < 4; ++i) {
        int id = idx0 + i;
        if (id < NBUCK) { bucket_start[id] = run; bucket_cursor[id] = run; run += c[i]; }
    }
    if (tid == 0) bucket_start[NBUCK] = total;
}

// scatter packed (local<<17|src) into bucket regions of tmp, LDS-staged
__global__ __launch_bounds__(256) void p1b_scatter(const int* __restrict__ src, const int* __restrict__ dst,
                                                   int* __restrict__ bucket_cursor, unsigned* __restrict__ tmp) {
    __shared__ unsigned stage[P1_CHUNK];        // 24 KB
    __shared__ unsigned short stageb[P1_CHUNK]; // 12 KB
    __shared__ int lhist[NBUCK];
    __shared__ int lbase[NBUCK];
    __shared__ int gbase[NBUCK];
    __shared__ int wpart[4];
    const int tid = threadIdx.x;
    const int lane = tid & 63;
    const int wid = tid >> 6;
    const long e0 = (long)blockIdx.x * P1_CHUNK;
    const int nvalid = (int)min((long)P1_CHUNK, (long)N_EDGES - e0);
    for (int i = tid; i < NBUCK; i += 256) lhist[i] = 0;
    __syncthreads();
    for (int i = tid; i < nvalid; i += 256) {
        atomicAdd(&lhist[dst[e0 + i] >> 7], 1);
    }
    __syncthreads();
    int c[4];
    const int idx0 = tid * 4;
    int tsum = 0;
#pragma unroll
    for (int i = 0; i < 4; ++i) {
        int id = idx0 + i;
        c[i] = (id < NBUCK) ? lhist[id] : 0;
        tsum += c[i];
    }
    int incl = tsum;
#pragma unroll
    for (int off = 1; off < 64; off <<= 1) {
        int t = __shfl_up(incl, (unsigned)off, 64);
        if (lane >= off) incl += t;
    }
    if (lane == 63) wpart[wid] = incl;
    __syncthreads();
    int wpre = 0;
#pragma unroll
    for (int w = 0; w < 4; ++w) { if (w < wid) wpre += wpart[w]; }
    int run = wpre + incl - tsum;
#pragma unroll
    for (int i = 0; i < 4; ++i) {
        int id = idx0 + i;
        if (id < NBUCK) { lbase[id] = run; run += c[i]; }
    }
    __syncthreads();
    for (int i = tid; i < NBUCK; i += 256) {
        int cnt = lhist[i];
        gbase[i] = (cnt > 0) ? atomicAdd(&bucket_cursor[i], cnt) : 0;
    }
    __syncthreads();
    for (int i = tid; i < NBUCK; i += 256) lhist[i] = 0;
    __syncthreads();
    for (int i = tid; i < nvalid; i += 256) {
        int d = dst[e0 + i];
        int s = src[e0 + i];
        int b = d >> 7;
        int r = atomicAdd(&lhist[b], 1);
        int pos = lbase[b] + r;
        stage[pos] = ((unsigned)(d & 127) << 17) | (unsigned)s;
        stageb[pos] = (unsigned short)b;
    }
    __syncthreads();
    for (int i = tid; i < nvalid; i += 256) {
        unsigned p = stage[i];
        int b = stageb[i];
        long gp = (long)gbase[b] + (i - lbase[b]);
        tmp[gp] = p;
    }
}

// per-bucket counting sort in LDS -> s_src coalesced; emits row_start and dis
__global__ __launch_bounds__(256) void p2_sort(const unsigned* __restrict__ tmp, const int* __restrict__ bucket_start,
                                               int* __restrict__ s_src, int* __restrict__ row_start,
                                               float* __restrict__ dis) {
    __shared__ unsigned pk[BCAP];   // 19.2 KB
    __shared__ int sorted[BCAP];    // 19.2 KB
    __shared__ int cnt128[128];
    __shared__ int pref[129];
    __shared__ int w2[2];
    const int b = blockIdx.x;
    const int tid = threadIdx.x;
    const int lane = tid & 63;
    const int base = bucket_start[b];
    const int end = bucket_start[b + 1];
    int cnt = end - base;
    if (cnt > BCAP) cnt = BCAP;
    const int nbase = b << 7;
    for (int i = tid; i < 128; i += 256) cnt128[i] = 0;
    __syncthreads();
    for (int i = tid; i < cnt; i += 256) {
        unsigned p = tmp[base + i];
        pk[i] = p;
        atomicAdd(&cnt128[p >> 17], 1);
    }
    __syncthreads();
    int v = (tid < 128) ? cnt128[tid] : 0;
    int incl = v;
#pragma unroll
    for (int off = 1; off < 64; off <<= 1) {
        int t = __shfl_up(incl, (unsigned)off, 64);
        if (lane >= off) incl += t;
    }
    if (tid < 128 && lane == 63) w2[tid >> 6] = incl;
    __syncthreads();
    if (tid < 128 && (tid >> 6) == 1) incl += w2[0];
    if (tid < 128) { pref[tid + 1] = incl; if (tid == 0) pref[0] = 0; }
    __syncthreads();
    const int nnodes = min(128, N_NODES - nbase);
    if (tid < nnodes) {
        row_start[nbase + tid] = base + pref[tid];
        dis[nbase + tid] = rsqrtf((float)cnt128[tid] + 1.0f);
    }
    if (b == NBUCK - 1 && tid == 0) row_start[N_NODES] = base + cnt;
    if (tid < 128) cnt128[tid] = pref[tid];
    __syncthreads();
    for (int i = tid; i < cnt; i += 256) {
        unsigned p = pk[i];
        int l = p >> 17;
        int pos = atomicAdd(&cnt128[l], 1);
        sorted[pos] = (int)(p & 0x1FFFFu);
    }
    __syncthreads();
    for (int i = tid; i < cnt; i += 256) s_src[base + i] = sorted[i];
}

// ---------------- dense lin with fused dis pre-scale, fp16 out ----------------
// Y[node,:] = (X[node,:] @ W) * dis[node]   (stored as half)

template <int K, int O>
__global__ __launch_bounds__(256) void lin_h_kernel(const float* __restrict__ X, const float* __restrict__ W,
                                                    const float* __restrict__ dis, __half* __restrict__ Y) {
    __shared__ float4 Wl[K * O / 4];
    const int tid = threadIdx.x;
    for (int i = tid; i < K * O / 4; i += 256) Wl[i] = reinterpret_cast<const float4*>(W)[i];
    __syncthreads();
    const int node = blockIdx.x * 256 + tid;
    if (node >= N_NODES) return;
    float4 acc[O / 4];
#pragma unroll
    for (int j = 0; j < O / 4; ++j) acc[j] = make_float4(0.f, 0.f, 0.f, 0.f);
    const float4* Xr = reinterpret_cast<const float4*>(X + (size_t)node * K);
#pragma unroll 2
    for (int k4 = 0; k4 < K / 4; ++k4) {
        float4 xv = Xr[k4];
#pragma unroll
        for (int kk = 0; kk < 4; ++kk) {
            float xs = f4c(xv, kk);
#pragma unroll
            for (int j = 0; j < O / 4; ++j) fma4(acc[j], xs, Wl[(k4 * 4 + kk) * (O / 4) + j]);
        }
    }
    const float s = dis[node];
    union { uint4 u[O / 8]; __half2 h[O / 2]; } pk;
#pragma unroll
    for (int j = 0; j < O / 4; ++j) {
        pk.h[2 * j]     = __floats2half2_rn(acc[j].x * s, acc[j].y * s);
        pk.h[2 * j + 1] = __floats2half2_rn(acc[j].z * s, acc[j].w * s);
    }
    uint4* Yr = reinterpret_cast<uint4*>(Y + (size_t)node * O);
#pragma unroll
    for (int j = 0; j < O / 8; ++j) Yr[j] = pk.u[j];
}

// ---------------- aggregation (gather-sum over pre-scaled fp16 H') ----------------
// Y[i,:] = maybe_relu( (H'[i,:] + sum_e H'[s_e,:]) * dis[i] + bias ) (+ Y[i,:] if RESIDUAL)

template <bool RELU, bool RESIDUAL>
__global__ __launch_bounds__(256) void agg64_kernel(const __half* __restrict__ Hp, float* __restrict__ Y,
                                                    const float* __restrict__ dis,
                                                    const int* __restrict__ row_start,
                                                    const int* __restrict__ s_src,
                                                    const float* __restrict__ bias) {
    const int tid = threadIdx.x;
    const int lane = tid & 63;
    const int wid = tid >> 6;
    const int node = blockIdx.x * 4 + wid;
    if (node >= N_NODES) return;
    const float di = dis[node];
    const int j = lane;
    float acc = __half2float(Hp[(size_t)node * 64 + j]);
    const int rs = row_start[node], re = row_start[node + 1];
    for (int b = rs; b < re; b += 64) {
        int idx = b + lane;
        int sv = (idx < re) ? s_src[idx] : 0;
        int m = min(64, re - b);
        int k = 0;
        for (; k + 4 <= m; k += 4) {
            int s0 = __shfl(sv, k);
            int s1 = __shfl(sv, k + 1);
            int s2 = __shfl(sv, k + 2);
            int s3 = __shfl(sv, k + 3);
            float h0 = __half2float(Hp[(size_t)s0 * 64 + j]);
            float h1 = __half2float(Hp[(size_t)s1 * 64 + j]);
            float h2 = __half2float(Hp[(size_t)s2 * 64 + j]);
            float h3 = __half2float(Hp[(size_t)s3 * 64 + j]);
            acc += (h0 + h1) + (h2 + h3);
        }
        for (; k < m; ++k) {
            int s0 = __shfl(sv, k);
            acc += __half2float(Hp[(size_t)s0 * 64 + j]);
        }
    }
    float out = acc * di + bias[j];
    if (RELU) out = fmaxf(out, 0.0f);
    if (RESIDUAL) out += Y[(size_t)node * 64 + j];
    Y[(size_t)node * 64 + j] = out;
}

// one wave per node, 4 edge-subgroups x 16 features; butterfly-reduce; fp16 out
__global__ __launch_bounds__(256) void agg16_kernel(const __half* __restrict__ Hp, __half* __restrict__ H3,
                                                    const float* __restrict__ dis,
                                                    const int* __restrict__ row_start,
                                                    const int* __restrict__ s_src,
                                                    const float* __restrict__ bias) {
    const int tid = threadIdx.x;
    const int lane = tid & 63;
    const int wid = tid >> 6;
    const int node = blockIdx.x * 4 + wid;
    if (node >= N_NODES) return;
    const int j = lane & 15;
    const int es = lane >> 4;
    float acc = (es == 0) ? __half2float(Hp[(size_t)node * 16 + j]) : 0.0f;
    const int rs = row_start[node], re = row_start[node + 1];
    int e = rs + es;
    for (; e + 4 < re; e += 8) {
        int s0 = s_src[e];
        int s1 = s_src[e + 4];
        float h0 = __half2float(Hp[(size_t)s0 * 16 + j]);
        float h1 = __half2float(Hp[(size_t)s1 * 16 + j]);
        acc += h0 + h1;
    }
    if (e < re) acc += __half2float(Hp[(size_t)s_src[e] * 16 + j]);
    acc += __shfl_xor(acc, 16, 64);
    acc += __shfl_xor(acc, 32, 64);
    if (es == 0) {
        float out = acc * dis[node] + bias[j];
        H3[(size_t)node * 16 + j] = __float2half_rn(out);
    }
}

// ---------------- edge MLP + log_softmax (fp16 h3 input) ----------------

__device__ __forceinline__ void cvt8(const uint4& u, float* f) {
    const __half2* h = reinterpret_cast<const __half2*>(&u);
#pragma unroll
    for (int i = 0; i < 4; ++i) {
        float2 t = __half22float2(h[i]);
        f[2 * i] = t.x; f[2 * i + 1] = t.y;
    }
}

__global__ __launch_bounds__(256) void edge_mlp_kernel(const __half* __restrict__ H3,
                                                       const int* __restrict__ src, const int* __restrict__ dst,
                                                       const float* __restrict__ fc1W, const float* __restrict__ fc1b,
                                                       const float* __restrict__ fc2W, const float* __restrict__ fc2b,
                                                       float* __restrict__ out) {
    __shared__ float4 sW1[32 * 4];   // fc1_W [32][16]
    __shared__ float4 sW2[16 * 4];   // fc2_W [16][16]
    __shared__ float4 sB1[4];
    __shared__ float4 sB2[4];
    const int tid = threadIdx.x;
    if (tid < 128) sW1[tid] = reinterpret_cast<const float4*>(fc1W)[tid];
    else if (tid < 192) sW2[tid - 128] = reinterpret_cast<const float4*>(fc2W)[tid - 128];
    else if (tid < 196) sB1[tid - 192] = reinterpret_cast<const float4*>(fc1b)[tid - 192];
    else if (tid < 200) sB2[tid - 196] = reinterpret_cast<const float4*>(fc2b)[tid - 196];
    __syncthreads();
    const int e = blockIdx.x * 256 + tid;
    if (e >= N_EDGES) return;
    const int s = src[e], d = dst[e];
    uint4 us0 = reinterpret_cast<const uint4*>(H3 + (size_t)s * 16)[0];
    uint4 us1 = reinterpret_cast<const uint4*>(H3 + (size_t)s * 16)[1];
    uint4 ud0 = reinterpret_cast<const uint4*>(H3 + (size_t)d * 16)[0];
    uint4 ud1 = reinterpret_cast<const uint4*>(H3 + (size_t)d * 16)[1];
    float hs[16], hd[16];
    cvt8(us0, hs); cvt8(us1, hs + 8);
    cvt8(ud0, hd); cvt8(ud1, hd + 8);
    float4 t[4];
#pragma unroll
    for (int q = 0; q < 4; ++q) t[q] = sB1[q];
#pragma unroll
    for (int k = 0; k < 16; ++k) {
        float a = hs[k];
#pragma unroll
        for (int q = 0; q < 4; ++q) fma4(t[q], a, sW1[k * 4 + q]);
    }
#pragma unroll
    for (int k = 0; k < 16; ++k) {
        float a = hd[k];
#pragma unroll
        for (int q = 0; q < 4; ++q) fma4(t[q], a, sW1[(16 + k) * 4 + q]);
    }
#pragma unroll
    for (int q = 0; q < 4; ++q) {
        t[q].x = fmaxf(t[q].x, 0.f); t[q].y = fmaxf(t[q].y, 0.f);
        t[q].z = fmaxf(t[q].z, 0.f); t[q].w = fmaxf(t[q].w, 0.f);
    }
    float4 o[4];
#pragma unroll
    for (int q = 0; q < 4; ++q) o[q] = sB2[q];
#pragma unroll
    for (int k = 0; k < 16; ++k) {
        float a = f4c(t[k >> 2], k & 3);
#pragma unroll
        for (int q = 0; q < 4; ++q) fma4(o[q], a, sW2[k * 4 + q]);
    }
    float m = o[0].x;
#pragma unroll
    for (int q = 0; q < 4; ++q) {
        m = fmaxf(m, o[q].x); m = fmaxf(m, o[q].y);
        m = fmaxf(m, o[q].z); m = fmaxf(m, o[q].w);
    }
    float sum = 0.f;
#pragma unroll
    for (int q = 0; q < 4; ++q) {
        sum += __expf(o[q].x - m); sum += __expf(o[q].y - m);
        sum += __expf(o[q].z - m); sum += __expf(o[q].w - m);
    }
    float ls = m + __logf(sum);
    float4* Or = reinterpret_cast<float4*>(out) + (size_t)e * 4;
#pragma unroll
    for (int q = 0; q < 4; ++q) {
        float4 r;
        r.x = o[q].x - ls; r.y = o[q].y - ls; r.z = o[q].z - ls; r.w = o[q].w - ls;
        Or[q] = r;
    }
}

// ---------------- launch ----------------

extern "C" void kernel_launch(void* const* d_in, const int* in_sizes, int n_in,
                              void* d_out, int out_size, void* d_ws, size_t ws_size,
                              hipStream_t stream) {
    (void)in_sizes; (void)n_in; (void)out_size; (void)ws_size;
    const float* x    = (const float*)d_in[0];
    const int* eidx   = (const int*)d_in[1];
    const float* W1   = (const float*)d_in[2];
    const float* b1   = (const float*)d_in[3];
    const float* W2   = (const float*)d_in[4];
    const float* b2   = (const float*)d_in[5];
    const float* W3   = (const float*)d_in[6];
    const float* b3   = (const float*)d_in[7];
    const float* fc1W = (const float*)d_in[8];
    const float* fc1b = (const float*)d_in[9];
    const float* fc2W = (const float*)d_in[10];
    const float* fc2b = (const float*)d_in[11];
    const int* src = eidx;
    const int* dst = eidx + N_EDGES;

    char* ws = (char*)d_ws;
    size_t off = 0;
    auto alloc = [&](size_t bytes) { size_t cur = off; off = (cur + bytes + 255) & ~(size_t)255; return cur; };
    int*   bhist         = (int*)(ws + alloc((size_t)NBUCK * 4));
    int*   bucket_start  = (int*)(ws + alloc((size_t)(NBUCK + 1) * 4));
    int*   bucket_cursor = (int*)(ws + alloc((size_t)NBUCK * 4));
    int*   row_start     = (int*)(ws + alloc((size_t)(N_NODES + 1) * 4));
    float* dis           = (float*)(ws + alloc((size_t)N_NODES * 4));
    int*   s_src         = (int*)(ws + alloc((size_t)N_EDGES * 4));
    __half* A            = (__half*)(ws + alloc((size_t)N_EDGES * 4));      // fp16 lin out / aliases tmp (both 12.8MB)
    float* B             = (float*)(ws + alloc((size_t)N_NODES * 64 * 4));  // fp32 h1/h2
    __half* H3           = (__half*)(ws + alloc((size_t)N_NODES * 16 * 2)); // fp16 h3
    unsigned* tmp        = (unsigned*)A;
    float* outp          = (float*)d_out;

    const int nblkN = (N_NODES + 255) / 256;
    const int nblkE = (N_EDGES + 255) / 256;

    // CSR build
    zero_kernel<<<(NBUCK + 255) / 256, 256, 0, stream>>>(bhist, NBUCK);
    p1a_hist<<<(N_EDGES + 8191) / 8192, 256, 0, stream>>>(dst, bhist);
    scan_buckets<<<1, 256, 0, stream>>>(bhist, bucket_start, bucket_cursor);
    p1b_scatter<<<(N_EDGES + P1_CHUNK - 1) / P1_CHUNK, 256, 0, stream>>>(src, dst, bucket_cursor, tmp);
    p2_sort<<<NBUCK, 256, 0, stream>>>(tmp, bucket_start, s_src, row_start, dis);

    // conv1: A = (x@W1)*dis ; B = relu(agg(A)*di + b1)
    lin_h_kernel<128, 64><<<nblkN, 256, 0, stream>>>(x, W1, dis, A);
    agg64_kernel<true, false><<<(N_NODES + 3) / 4, 256, 0, stream>>>(A, B, dis, row_start, s_src, b1);
    // conv2: A = (B@W2)*dis ; B = relu(agg(A)*di + b2) + B
    lin_h_kernel<64, 64><<<nblkN, 256, 0, stream>>>(B, W2, dis, A);
    agg64_kernel<true, true><<<(N_NODES + 3) / 4, 256, 0, stream>>>(A, B, dis, row_start, s_src, b2);
    // conv3: A16 = (B@W3)*dis ; H3 = agg(A16)*di + b3
    lin_h_kernel<64, 16><<<nblkN, 256, 0, stream>>>(B, W3, dis, A);
    agg16_kernel<<<(N_NODES + 3) / 4, 256, 0, stream>>>(A, H3, dis, row_start, s_src, b3);
    // edge MLP + log_softmax
    edge_mlp_kernel<<<nblkE, 256, 0, stream>>>(H3, src, dst, fc1W, fc1b, fc2W, fc2b, outp);
}

// Round 4
// 429.755 us; speedup vs baseline: 2.9132x; 1.1063x over previous
//
#include <hip/hip_runtime.h>
#include <hip/hip_bf16.h>
#include <hip/hip_fp16.h>

#define N_NODES 100000
#define N_EDGES 3200000
#define NBUCK 782          // ceil(100000/128) buckets of 128 nodes
#define P1_CHUNK 6144      // edges per p1b block
#define BCAP 4800          // max edges per bucket (mean 4092, sd ~64)

typedef _Float16 half4f __attribute__((ext_vector_type(4)));
typedef float floatx4 __attribute__((ext_vector_type(4)));

__device__ __forceinline__ float f4c(const float4& v, int k) {
    switch (k & 3) { case 0: return v.x; case 1: return v.y; case 2: return v.z; default: return v.w; }
}
__device__ __forceinline__ void fma4(float4& a, float s, const float4& w) {
    a.x += s * w.x; a.y += s * w.y; a.z += s * w.z; a.w += s * w.w;
}

// ---------------- CSR build (2-level counting sort, coalesced writes) ----------------

__global__ __launch_bounds__(256) void zero_kernel(int* __restrict__ p, int n) {
    int i = blockIdx.x * 256 + threadIdx.x;
    if (i < n) p[i] = 0;
}

__global__ __launch_bounds__(256) void p1a_hist(const int* __restrict__ dst, int* __restrict__ bhist) {
    __shared__ int lhist[NBUCK];
    const int tid = threadIdx.x;
    for (int i = tid; i < NBUCK; i += 256) lhist[i] = 0;
    __syncthreads();
    const long e0 = (long)blockIdx.x * 8192;
    for (int i = tid; i < 8192; i += 256) {
        long e = e0 + i;
        if (e < N_EDGES) atomicAdd(&lhist[dst[e] >> 7], 1);
    }
    __syncthreads();
    for (int i = tid; i < NBUCK; i += 256) {
        int c = lhist[i];
        if (c > 0) atomicAdd(&bhist[i], c);
    }
}

__global__ __launch_bounds__(256) void scan_buckets(const int* __restrict__ bhist,
                                                    int* __restrict__ bucket_start,
                                                    int* __restrict__ bucket_cursor) {
    __shared__ int wpart[4];
    const int tid = threadIdx.x;
    const int lane = tid & 63;
    const int wid = tid >> 6;
    int c[4];
    const int idx0 = tid * 4;
    int tsum = 0;
#pragma unroll
    for (int i = 0; i < 4; ++i) {
        int id = idx0 + i;
        c[i] = (id < NBUCK) ? bhist[id] : 0;
        tsum += c[i];
    }
    int incl = tsum;
#pragma unroll
    for (int off = 1; off < 64; off <<= 1) {
        int t = __shfl_up(incl, (unsigned)off, 64);
        if (lane >= off) incl += t;
    }
    if (lane == 63) wpart[wid] = incl;
    __syncthreads();
    int wpre = 0, total = 0;
#pragma unroll
    for (int w = 0; w < 4; ++w) { int sv = wpart[w]; if (w < wid) wpre += sv; total += sv; }
    int run = wpre + incl - tsum;
#pragma unroll
    for (int i = 0; i < 4; ++i) {
        int id = idx0 + i;
        if (id < NBUCK) { bucket_start[id] = run; bucket_cursor[id] = run; run += c[i]; }
    }
    if (tid == 0) bucket_start[NBUCK] = total;
}

// scatter packed (local<<17|src) into bucket regions of tmp, LDS-staged
__global__ __launch_bounds__(256) void p1b_scatter(const int* __restrict__ src, const int* __restrict__ dst,
                                                   int* __restrict__ bucket_cursor, unsigned* __restrict__ tmp) {
    __shared__ unsigned stage[P1_CHUNK];        // 24 KB
    __shared__ unsigned short stageb[P1_CHUNK]; // 12 KB
    __shared__ int lhist[NBUCK];
    __shared__ int lbase[NBUCK];
    __shared__ int gbase[NBUCK];
    __shared__ int wpart[4];
    const int tid = threadIdx.x;
    const int lane = tid & 63;
    const int wid = tid >> 6;
    const long e0 = (long)blockIdx.x * P1_CHUNK;
    const int nvalid = (int)min((long)P1_CHUNK, (long)N_EDGES - e0);
    for (int i = tid; i < NBUCK; i += 256) lhist[i] = 0;
    __syncthreads();
    for (int i = tid; i < nvalid; i += 256) {
        atomicAdd(&lhist[dst[e0 + i] >> 7], 1);
    }
    __syncthreads();
    int c[4];
    const int idx0 = tid * 4;
    int tsum = 0;
#pragma unroll
    for (int i = 0; i < 4; ++i) {
        int id = idx0 + i;
        c[i] = (id < NBUCK) ? lhist[id] : 0;
        tsum += c[i];
    }
    int incl = tsum;
#pragma unroll
    for (int off = 1; off < 64; off <<= 1) {
        int t = __shfl_up(incl, (unsigned)off, 64);
        if (lane >= off) incl += t;
    }
    if (lane == 63) wpart[wid] = incl;
    __syncthreads();
    int wpre = 0;
#pragma unroll
    for (int w = 0; w < 4; ++w) { if (w < wid) wpre += wpart[w]; }
    int run = wpre + incl - tsum;
#pragma unroll
    for (int i = 0; i < 4; ++i) {
        int id = idx0 + i;
        if (id < NBUCK) { lbase[id] = run; run += c[i]; }
    }
    __syncthreads();
    for (int i = tid; i < NBUCK; i += 256) {
        int cnt = lhist[i];
        gbase[i] = (cnt > 0) ? atomicAdd(&bucket_cursor[i], cnt) : 0;
    }
    __syncthreads();
    for (int i = tid; i < NBUCK; i += 256) lhist[i] = 0;
    __syncthreads();
    for (int i = tid; i < nvalid; i += 256) {
        int d = dst[e0 + i];
        int s = src[e0 + i];
        int b = d >> 7;
        int r = atomicAdd(&lhist[b], 1);
        int pos = lbase[b] + r;
        stage[pos] = ((unsigned)(d & 127) << 17) | (unsigned)s;
        stageb[pos] = (unsigned short)b;
    }
    __syncthreads();
    for (int i = tid; i < nvalid; i += 256) {
        unsigned p = stage[i];
        int b = stageb[i];
        long gp = (long)gbase[b] + (i - lbase[b]);
        tmp[gp] = p;
    }
}

// per-bucket counting sort in LDS -> s_src coalesced; emits row_start and dis
__global__ __launch_bounds__(256) void p2_sort(const unsigned* __restrict__ tmp, const int* __restrict__ bucket_start,
                                               int* __restrict__ s_src, int* __restrict__ row_start,
                                               float* __restrict__ dis) {
    __shared__ unsigned pk[BCAP];   // 19.2 KB
    __shared__ int sorted[BCAP];    // 19.2 KB
    __shared__ int cnt128[128];
    __shared__ int pref[129];
    __shared__ int w2[2];
    const int b = blockIdx.x;
    const int tid = threadIdx.x;
    const int lane = tid & 63;
    const int base = bucket_start[b];
    const int end = bucket_start[b + 1];
    int cnt = end - base;
    if (cnt > BCAP) cnt = BCAP;
    const int nbase = b << 7;
    for (int i = tid; i < 128; i += 256) cnt128[i] = 0;
    __syncthreads();
    for (int i = tid; i < cnt; i += 256) {
        unsigned p = tmp[base + i];
        pk[i] = p;
        atomicAdd(&cnt128[p >> 17], 1);
    }
    __syncthreads();
    int v = (tid < 128) ? cnt128[tid] : 0;
    int incl = v;
#pragma unroll
    for (int off = 1; off < 64; off <<= 1) {
        int t = __shfl_up(incl, (unsigned)off, 64);
        if (lane >= off) incl += t;
    }
    if (tid < 128 && lane == 63) w2[tid >> 6] = incl;
    __syncthreads();
    if (tid < 128 && (tid >> 6) == 1) incl += w2[0];
    if (tid < 128) { pref[tid + 1] = incl; if (tid == 0) pref[0] = 0; }
    __syncthreads();
    const int nnodes = min(128, N_NODES - nbase);
    if (tid < nnodes) {
        row_start[nbase + tid] = base + pref[tid];
        dis[nbase + tid] = rsqrtf((float)cnt128[tid] + 1.0f);
    }
    if (b == NBUCK - 1 && tid == 0) row_start[N_NODES] = base + cnt;
    if (tid < 128) cnt128[tid] = pref[tid];
    __syncthreads();
    for (int i = tid; i < cnt; i += 256) {
        unsigned p = pk[i];
        int l = p >> 17;
        int pos = atomicAdd(&cnt128[l], 1);
        sorted[pos] = (int)(p & 0x1FFFFu);
    }
    __syncthreads();
    for (int i = tid; i < cnt; i += 256) s_src[base + i] = sorted[i];
}

// ---------------- dense lin with fused dis pre-scale, fp16 out ----------------

template <int K, int O>
__global__ __launch_bounds__(256) void lin_h_kernel(const float* __restrict__ X, const float* __restrict__ W,
                                                    const float* __restrict__ dis, __half* __restrict__ Y) {
    __shared__ float4 Wl[K * O / 4];
    const int tid = threadIdx.x;
    for (int i = tid; i < K * O / 4; i += 256) Wl[i] = reinterpret_cast<const float4*>(W)[i];
    __syncthreads();
    const int node = blockIdx.x * 256 + tid;
    if (node >= N_NODES) return;
    float4 acc[O / 4];
#pragma unroll
    for (int j = 0; j < O / 4; ++j) acc[j] = make_float4(0.f, 0.f, 0.f, 0.f);
    const float4* Xr = reinterpret_cast<const float4*>(X + (size_t)node * K);
#pragma unroll 2
    for (int k4 = 0; k4 < K / 4; ++k4) {
        float4 xv = Xr[k4];
#pragma unroll
        for (int kk = 0; kk < 4; ++kk) {
            float xs = f4c(xv, kk);
#pragma unroll
            for (int j = 0; j < O / 4; ++j) fma4(acc[j], xs, Wl[(k4 * 4 + kk) * (O / 4) + j]);
        }
    }
    const float s = dis[node];
    union { uint4 u[O / 8]; __half2 h[O / 2]; } pk;
#pragma unroll
    for (int j = 0; j < O / 4; ++j) {
        pk.h[2 * j]     = __floats2half2_rn(acc[j].x * s, acc[j].y * s);
        pk.h[2 * j + 1] = __floats2half2_rn(acc[j].z * s, acc[j].w * s);
    }
    uint4* Yr = reinterpret_cast<uint4*>(Y + (size_t)node * O);
#pragma unroll
    for (int j = 0; j < O / 8; ++j) Yr[j] = pk.u[j];
}

// ---------------- aggregation (gather-sum over pre-scaled fp16 H') ----------------

template <bool RELU, bool RESIDUAL>
__global__ __launch_bounds__(256) void agg64_kernel(const __half* __restrict__ Hp, float* __restrict__ Y,
                                                    const float* __restrict__ dis,
                                                    const int* __restrict__ row_start,
                                                    const int* __restrict__ s_src,
                                                    const float* __restrict__ bias) {
    const int tid = threadIdx.x;
    const int lane = tid & 63;
    const int wid = tid >> 6;
    const int node = blockIdx.x * 4 + wid;
    if (node >= N_NODES) return;
    const float di = dis[node];
    const int j = lane;
    float acc = __half2float(Hp[(size_t)node * 64 + j]);
    const int rs = row_start[node], re = row_start[node + 1];
    for (int b = rs; b < re; b += 64) {
        int idx = b + lane;
        int sv = (idx < re) ? s_src[idx] : 0;
        int m = min(64, re - b);
        int k = 0;
        for (; k + 4 <= m; k += 4) {
            int s0 = __shfl(sv, k);
            int s1 = __shfl(sv, k + 1);
            int s2 = __shfl(sv, k + 2);
            int s3 = __shfl(sv, k + 3);
            float h0 = __half2float(Hp[(size_t)s0 * 64 + j]);
            float h1 = __half2float(Hp[(size_t)s1 * 64 + j]);
            float h2 = __half2float(Hp[(size_t)s2 * 64 + j]);
            float h3 = __half2float(Hp[(size_t)s3 * 64 + j]);
            acc += (h0 + h1) + (h2 + h3);
        }
        for (; k < m; ++k) {
            int s0 = __shfl(sv, k);
            acc += __half2float(Hp[(size_t)s0 * 64 + j]);
        }
    }
    float out = acc * di + bias[j];
    if (RELU) out = fmaxf(out, 0.0f);
    if (RESIDUAL) out += Y[(size_t)node * 64 + j];
    Y[(size_t)node * 64 + j] = out;
}

__global__ __launch_bounds__(256) void agg16_kernel(const __half* __restrict__ Hp, __half* __restrict__ H3,
                                                    const float* __restrict__ dis,
                                                    const int* __restrict__ row_start,
                                                    const int* __restrict__ s_src,
                                                    const float* __restrict__ bias) {
    const int tid = threadIdx.x;
    const int lane = tid & 63;
    const int wid = tid >> 6;
    const int node = blockIdx.x * 4 + wid;
    if (node >= N_NODES) return;
    const int j = lane & 15;
    const int es = lane >> 4;
    float acc = (es == 0) ? __half2float(Hp[(size_t)node * 16 + j]) : 0.0f;
    const int rs = row_start[node], re = row_start[node + 1];
    int e = rs + es;
    for (; e + 4 < re; e += 8) {
        int s0 = s_src[e];
        int s1 = s_src[e + 4];
        float h0 = __half2float(Hp[(size_t)s0 * 16 + j]);
        float h1 = __half2float(Hp[(size_t)s1 * 16 + j]);
        acc += h0 + h1;
    }
    if (e < re) acc += __half2float(Hp[(size_t)s_src[e] * 16 + j]);
    acc += __shfl_xor(acc, 16, 64);
    acc += __shfl_xor(acc, 32, 64);
    if (es == 0) {
        float out = acc * dis[node] + bias[j];
        H3[(size_t)node * 16 + j] = __float2half_rn(out);
    }
}

// ---------------- edge MLP + log_softmax: MFMA, weights in registers ----------------
// Per wave: 16 edges. D1[out_c, edge] = W1^T . [hs;hd]^T + b1  (two K=16 MFMAs)
// D2[c', edge] = W2^T . relu(D1) + b2 (one MFMA; D1's C/D layout == B-fragment layout)

__global__ __launch_bounds__(256) void edge_mlp_kernel(const __half* __restrict__ H3,
                                                       const int* __restrict__ src, const int* __restrict__ dst,
                                                       const float* __restrict__ fc1W, const float* __restrict__ fc1b,
                                                       const float* __restrict__ fc2W, const float* __restrict__ fc2b,
                                                       float* __restrict__ out) {
    const int lane = threadIdx.x & 63;
    const int g = lane >> 4;       // lane group 0..3
    const int c = lane & 15;       // edge-slot / weight column
    // weight fragments (A operand: lane holds A[row=c, k=4g+j] = W[4g+j][c])
    half4f a1a, a1b, a2;
    floatx4 cb1, cb2;
#pragma unroll
    for (int j = 0; j < 4; ++j) {
        a1a[j] = (_Float16)fc1W[(4 * g + j) * 16 + c];
        a1b[j] = (_Float16)fc1W[(16 + 4 * g + j) * 16 + c];
        a2[j]  = (_Float16)fc2W[(4 * g + j) * 16 + c];
        cb1[j] = fc1b[4 * g + j];
        cb2[j] = fc2b[4 * g + j];
    }
    const int wave_id = blockIdx.x * 4 + ((int)threadIdx.x >> 6);
    const int nwaves = gridDim.x * 4;
    for (long eb = (long)wave_id * 16; eb < N_EDGES; eb += (long)nwaves * 16) {
        const int e = (int)eb + c;
        const int si = src[e];
        const int di = dst[e];
        // B fragments: lane holds B[k=4g+j, col=c] = h[edge=c][feat=4g+j] -> 8B vector load
        half4f bs = *reinterpret_cast<const half4f*>(H3 + (size_t)si * 16 + 4 * g);
        half4f bd = *reinterpret_cast<const half4f*>(H3 + (size_t)di * 16 + 4 * g);
        floatx4 t = cb1;
        t = __builtin_amdgcn_mfma_f32_16x16x16f16(a1a, bs, t, 0, 0, 0);
        t = __builtin_amdgcn_mfma_f32_16x16x16f16(a1b, bd, t, 0, 0, 0);
        half4f tb;
#pragma unroll
        for (int i = 0; i < 4; ++i) tb[i] = (_Float16)fmaxf(t[i], 0.0f);
        floatx4 o = __builtin_amdgcn_mfma_f32_16x16x16f16(a2, tb, cb2, 0, 0, 0);
        // log_softmax over out_c (rows): 4 in-lane + lane-groups via shfl_xor
        float m = fmaxf(fmaxf(o[0], o[1]), fmaxf(o[2], o[3]));
        m = fmaxf(m, __shfl_xor(m, 16, 64));
        m = fmaxf(m, __shfl_xor(m, 32, 64));
        float s = __expf(o[0] - m) + __expf(o[1] - m) + __expf(o[2] - m) + __expf(o[3] - m);
        s += __shfl_xor(s, 16, 64);
        s += __shfl_xor(s, 32, 64);
        const float ls = m + __logf(s);
        floatx4 r;
#pragma unroll
        for (int i = 0; i < 4; ++i) r[i] = o[i] - ls;
        // lane writes out[e][4g..4g+3]; wave covers contiguous 1KB
        *reinterpret_cast<floatx4*>(out + (size_t)e * 16 + 4 * g) = r;
    }
}

// ---------------- launch ----------------

extern "C" void kernel_launch(void* const* d_in, const int* in_sizes, int n_in,
                              void* d_out, int out_size, void* d_ws, size_t ws_size,
                              hipStream_t stream) {
    (void)in_sizes; (void)n_in; (void)out_size; (void)ws_size;
    const float* x    = (const float*)d_in[0];
    const int* eidx   = (const int*)d_in[1];
    const float* W1   = (const float*)d_in[2];
    const float* b1   = (const float*)d_in[3];
    const float* W2   = (const float*)d_in[4];
    const float* b2   = (const float*)d_in[5];
    const float* W3   = (const float*)d_in[6];
    const float* b3   = (const float*)d_in[7];
    const float* fc1W = (const float*)d_in[8];
    const float* fc1b = (const float*)d_in[9];
    const float* fc2W = (const float*)d_in[10];
    const float* fc2b = (const float*)d_in[11];
    const int* src = eidx;
    const int* dst = eidx + N_EDGES;

    char* ws = (char*)d_ws;
    size_t off = 0;
    auto alloc = [&](size_t bytes) { size_t cur = off; off = (cur + bytes + 255) & ~(size_t)255; return cur; };
    int*   bhist         = (int*)(ws + alloc((size_t)NBUCK * 4));
    int*   bucket_start  = (int*)(ws + alloc((size_t)(NBUCK + 1) * 4));
    int*   bucket_cursor = (int*)(ws + alloc((size_t)NBUCK * 4));
    int*   row_start     = (int*)(ws + alloc((size_t)(N_NODES + 1) * 4));
    float* dis           = (float*)(ws + alloc((size_t)N_NODES * 4));
    int*   s_src         = (int*)(ws + alloc((size_t)N_EDGES * 4));
    __half* A            = (__half*)(ws + alloc((size_t)N_EDGES * 4));      // fp16 lin out / aliases tmp
    float* B             = (float*)(ws + alloc((size_t)N_NODES * 64 * 4));  // fp32 h1/h2
    __half* H3           = (__half*)(ws + alloc((size_t)N_NODES * 16 * 2)); // fp16 h3
    unsigned* tmp        = (unsigned*)A;
    float* outp          = (float*)d_out;

    const int nblkN = (N_NODES + 255) / 256;

    // CSR build
    zero_kernel<<<(NBUCK + 255) / 256, 256, 0, stream>>>(bhist, NBUCK);
    p1a_hist<<<(N_EDGES + 8191) / 8192, 256, 0, stream>>>(dst, bhist);
    scan_buckets<<<1, 256, 0, stream>>>(bhist, bucket_start, bucket_cursor);
    p1b_scatter<<<(N_EDGES + P1_CHUNK - 1) / P1_CHUNK, 256, 0, stream>>>(src, dst, bucket_cursor, tmp);
    p2_sort<<<NBUCK, 256, 0, stream>>>(tmp, bucket_start, s_src, row_start, dis);

    // conv1: A = (x@W1)*dis ; B = relu(agg(A)*di + b1)
    lin_h_kernel<128, 64><<<nblkN, 256, 0, stream>>>(x, W1, dis, A);
    agg64_kernel<true, false><<<(N_NODES + 3) / 4, 256, 0, stream>>>(A, B, dis, row_start, s_src, b1);
    // conv2: A = (B@W2)*dis ; B = relu(agg(A)*di + b2) + B
    lin_h_kernel<64, 64><<<nblkN, 256, 0, stream>>>(B, W2, dis, A);
    agg64_kernel<true, true><<<(N_NODES + 3) / 4, 256, 0, stream>>>(A, B, dis, row_start, s_src, b2);
    // conv3: A16 = (B@W3)*dis ; H3 = agg(A16)*di + b3
    lin_h_kernel<64, 16><<<nblkN, 256, 0, stream>>>(B, W3, dis, A);
    agg16_kernel<<<(N_NODES + 3) / 4, 256, 0, stream>>>(A, H3, dis, row_start, s_src, b3);
    // edge MLP + log_softmax (MFMA)
    edge_mlp_kernel<<<2048, 256, 0, stream>>>(H3, src, dst, fc1W, fc1b, fc2W, fc2b, outp);
}